// Round 8
// baseline (216.683 us; speedup 1.0000x reference)
//
#include <hip/hip_runtime.h>
#include <hip/hip_fp16.h>

#define D_FEAT 64
#define NPB 128            // nodes per bucket (node >> 7)
#define NBMAX 1024         // padded bucket count (pow2)
#define CHUNK 2048         // edges per partition block
#define EPT 8              // CHUNK / 256
#define CAPB 2816          // sortagg LDS edge capacity (mean 2046 + ~17 sigma)
#define RPT 6              // ceil(CAPB / 512)

// ---------------- zero ----------------
__global__ void zero_ints(int* __restrict__ p, int n) {
    int i = blockIdx.x * blockDim.x + threadIdx.x;
    int stride = gridDim.x * blockDim.x;
    for (int j = i; j < n; j += stride) p[j] = 0;
}

// exclusive scan over 256 threads, 2 barriers (wsum4 = shared int[4])
__device__ __forceinline__ int excl_scan_256(int v, int* wsum4) {
    int lane = threadIdx.x & 63, w = threadIdx.x >> 6;
    int inc = v;
    #pragma unroll
    for (int off = 1; off < 64; off <<= 1) {
        int y = __shfl_up(inc, off);
        if (lane >= off) inc += y;
    }
    if (lane == 63) wsum4[w] = inc;
    __syncthreads();
    int add = 0;
    #pragma unroll
    for (int i = 0; i < 3; ++i) if (i < w) add += wsum4[i];
    int r = add + inc - v;
    __syncthreads();
    return r;
}

// ---------------- bucket counts for BOTH sides ----------------
__global__ __launch_bounds__(256) void bcnt_kernel(
        const int* __restrict__ src, const int* __restrict__ dst, int n_edges,
        int* __restrict__ dbcnt8, int* __restrict__ sbcnt8) {
    __shared__ int ld[NBMAX];
    __shared__ int ls[NBMAX];
    int t = threadIdx.x;
    for (int i = t; i < NBMAX; i += 256) { ld[i] = 0; ls[i] = 0; }
    __syncthreads();
    int i0 = blockIdx.x * blockDim.x + t;
    int stride = gridDim.x * blockDim.x;
    for (int e = i0; e < n_edges; e += stride) {
        atomicAdd(&ld[dst[e] >> 7], 1);
        atomicAdd(&ls[src[e] >> 7], 1);
    }
    __syncthreads();
    int* dmy = dbcnt8 + (blockIdx.x & 7) * NBMAX;
    int* smy = sbcnt8 + (blockIdx.x & 7) * NBMAX;
    for (int i = t; i < NBMAX; i += 256) {
        if (ld[i]) atomicAdd(&dmy[i], ld[i]);
        if (ls[i]) atomicAdd(&smy[i], ls[i]);
    }
}

// ---------------- dual exclusive scan: block 0 = dst side, block 1 = src side ----
__global__ void scan2_kernel(const int* __restrict__ dbcnt8, const int* __restrict__ sbcnt8,
                             int* __restrict__ dbstart, int* __restrict__ gcursor,
                             int* __restrict__ sbstart, int* __restrict__ scursor,
                             int n_edges) {
    __shared__ int wsum[16];
    int t = threadIdx.x, lane = t & 63, w = t >> 6;
    const int* c8 = (blockIdx.x == 0) ? dbcnt8 : sbcnt8;
    int* bs = (blockIdx.x == 0) ? dbstart : sbstart;
    int* cur = (blockIdx.x == 0) ? gcursor : scursor;
    int v = 0;
    #pragma unroll
    for (int c = 0; c < 8; ++c) v += c8[c * NBMAX + t];
    int inc = v;
    #pragma unroll
    for (int off = 1; off < 64; off <<= 1) {
        int y = __shfl_up(inc, off);
        if (lane >= off) inc += y;
    }
    if (lane == 63) wsum[w] = inc;
    __syncthreads();
    int add = 0;
    #pragma unroll
    for (int i = 0; i < 15; ++i) if (i < w) add += wsum[i];
    int ex = add + inc - v;
    bs[t] = ex;
    cur[t] = ex;
    if (t == NBMAX - 1) bs[NBMAX] = n_edges;
}

// ---------------- fused dual partition (ldelta overlays lhist) ----------------
__global__ __launch_bounds__(256) void dualpart_kernel(
        const int* __restrict__ src, const int* __restrict__ dst, int n_edges,
        int* __restrict__ gcursor, int* __restrict__ scursor,
        int* __restrict__ arrA, unsigned char* __restrict__ arrS) {
    __shared__ int lhist[NBMAX];          // doubles as ldelta after scan
    __shared__ int lstart[NBMAX];
    __shared__ int lcur[NBMAX];
    __shared__ int wsum4[4];
    __shared__ int pkLDS[CHUNK];
    __shared__ unsigned short bktLDS[CHUNK];

    int t = threadIdx.x;
    long long cbase = (long long)blockIdx.x * CHUNK;
    int cnt = (n_edges - cbase < CHUNK) ? (int)(n_edges - cbase) : CHUNK;

    for (int i = t; i < NBMAX; i += 256) lhist[i] = 0;
    __syncthreads();

    int ssrc[EPT], sdst[EPT];
    #pragma unroll
    for (int i = 0; i < EPT; ++i) {
        long long e = cbase + t + i * 256;
        if (e < n_edges) {
            ssrc[i] = src[e];
            sdst[i] = dst[e];
            atomicAdd(&lhist[sdst[i] >> 7], 1);
        } else {
            ssrc[i] = -1;
            sdst[i] = -1;
        }
    }
    __syncthreads();

    // ---- phase D ----
    int b0 = 4 * t;
    int h0 = lhist[b0], h1 = lhist[b0 + 1], h2v = lhist[b0 + 2], h3 = lhist[b0 + 3];
    int tot = h0 + h1 + h2v + h3;
    int ex = excl_scan_256(tot, wsum4);
    int ls0 = ex, ls1 = ex + h0, ls2 = ex + h0 + h1, ls3 = ex + h0 + h1 + h2v;
    lstart[b0] = ls0; lstart[b0 + 1] = ls1; lstart[b0 + 2] = ls2; lstart[b0 + 3] = ls3;
    lcur[b0] = ls0; lcur[b0 + 1] = ls1; lcur[b0 + 2] = ls2; lcur[b0 + 3] = ls3;
    if (h0) lhist[b0] = atomicAdd(&gcursor[b0], h0) - ls0;
    if (h1) lhist[b0 + 1] = atomicAdd(&gcursor[b0 + 1], h1) - ls1;
    if (h2v) lhist[b0 + 2] = atomicAdd(&gcursor[b0 + 2], h2v) - ls2;
    if (h3) lhist[b0 + 3] = atomicAdd(&gcursor[b0 + 3], h3) - ls3;
    __syncthreads();
    #pragma unroll
    for (int i = 0; i < EPT; ++i) {
        if (sdst[i] >= 0) {
            int b = sdst[i] >> 7;
            int slot = atomicAdd(&lcur[b], 1);
            pkLDS[slot] = (ssrc[i] << 7) | (sdst[i] & 127);
            bktLDS[slot] = (unsigned short)b;
        }
    }
    __syncthreads();
    for (int j = t; j < cnt; j += 256) {
        int b = bktLDS[j];
        arrA[j + lhist[b]] = pkLDS[j];
    }
    __syncthreads();

    // ---- phase S ----
    for (int i = t; i < NBMAX; i += 256) lhist[i] = 0;
    __syncthreads();
    #pragma unroll
    for (int i = 0; i < EPT; ++i) {
        if (ssrc[i] >= 0) atomicAdd(&lhist[ssrc[i] >> 7], 1);
    }
    __syncthreads();
    h0 = lhist[b0]; h1 = lhist[b0 + 1]; h2v = lhist[b0 + 2]; h3 = lhist[b0 + 3];
    tot = h0 + h1 + h2v + h3;
    ex = excl_scan_256(tot, wsum4);
    ls0 = ex; ls1 = ex + h0; ls2 = ex + h0 + h1; ls3 = ex + h0 + h1 + h2v;
    lcur[b0] = ls0; lcur[b0 + 1] = ls1; lcur[b0 + 2] = ls2; lcur[b0 + 3] = ls3;
    if (h0) lhist[b0] = atomicAdd(&scursor[b0], h0) - ls0;
    if (h1) lhist[b0 + 1] = atomicAdd(&scursor[b0 + 1], h1) - ls1;
    if (h2v) lhist[b0 + 2] = atomicAdd(&scursor[b0 + 2], h2v) - ls2;
    if (h3) lhist[b0 + 3] = atomicAdd(&scursor[b0 + 3], h3) - ls3;
    __syncthreads();
    unsigned char* stg = (unsigned char*)pkLDS;
    #pragma unroll
    for (int i = 0; i < EPT; ++i) {
        if (ssrc[i] >= 0) {
            int b = ssrc[i] >> 7;
            int slot = atomicAdd(&lcur[b], 1);
            stg[slot] = (unsigned char)(ssrc[i] & 127);
            bktLDS[slot] = (unsigned short)b;
        }
    }
    __syncthreads();
    for (int j = t; j < cnt; j += 256) {
        int b = bktLDS[j];
        arrS[j + lhist[b]] = stg[j];
    }
}

// ---------------- fused out-degree + h prepass: one block per src bucket ----------
__global__ __launch_bounds__(256) void prep_kernel(
        const float4* __restrict__ emb4, const unsigned char* __restrict__ arrS,
        const int* __restrict__ sbstart, uint2* __restrict__ h2, int n_nodes) {
    __shared__ int lh[NPB];
    __shared__ float lsc[NPB];
    int b = blockIdx.x, t = threadIdx.x;
    int s = sbstart[b], e = sbstart[b + 1];
    if (t < NPB) lh[t] = 0;
    __syncthreads();
    for (int i = s + t; i < e; i += 256) atomicAdd(&lh[arrS[i]], 1);
    __syncthreads();
    if (t < NPB) {
        int od = lh[t];
        lsc[t] = rsqrtf((float)(od > 1 ? od : 1));
    }
    __syncthreads();
    int nbase = b * NPB;
    int r = t >> 4, c = t & 15;
    for (int r0 = 0; r0 < NPB; r0 += 16) {
        int row = r0 + r;
        int node = nbase + row;
        if (node < n_nodes) {
            float sc = lsc[row];
            float4 v = emb4[(size_t)node * 16 + c];
            __half2 a = __floats2half2_rn(v.x * sc, v.y * sc);
            __half2 bb = __floats2half2_rn(v.z * sc, v.w * sc);
            union { __half2 h; unsigned int u; } ua, ub;
            ua.h = a; ub.h = bb;
            uint2 rr; rr.x = ua.u; rr.y = ub.u;
            h2[(size_t)node * 16 + c] = rr;
        }
    }
    if (b == 0 && t < 16) {
        uint2 z; z.x = 0; z.y = 0;
        h2[(size_t)n_nodes * 16 + t] = z;
    }
}

// ---------------- fused sort + aggregate: one block per dst bucket ----------------
__global__ __launch_bounds__(512) void sortagg_kernel(
        const uint2* __restrict__ h2, const int* __restrict__ arrA,
        const int* __restrict__ dbstart, float* __restrict__ out, int n_nodes) {
    __shared__ int lh[NPB];
    __shared__ int lst[NPB];
    __shared__ int lcur[NPB];
    __shared__ int srcS[CAPB];
    int b = blockIdx.x, t = threadIdx.x;
    int s = dbstart[b], e = dbstart[b + 1];
    int cnt = e - s;
    bool fit = (cnt <= CAPB);

    if (t < NPB) lh[t] = 0;
    __syncthreads();
    int pkreg[RPT];
    if (fit) {
        #pragma unroll
        for (int i = 0; i < RPT; ++i) {
            int idx = t + i * 512;
            pkreg[i] = (idx < cnt) ? arrA[s + idx] : -1;
            if (pkreg[i] >= 0) atomicAdd(&lh[pkreg[i] & 127], 1);
        }
    } else {
        for (int i = t; i < cnt; i += 512) atomicAdd(&lh[arrA[s + i] & 127], 1);
    }
    __syncthreads();
    if (t < 64) {
        int l0 = lh[t], l1 = lh[t + 64];
        int a = l0;
        for (int off = 1; off < 64; off <<= 1) { int y = __shfl_up(a, off); if (t >= off) a += y; }
        int tot0 = __shfl(a, 63);
        int c = l1;
        for (int off = 1; off < 64; off <<= 1) { int y = __shfl_up(c, off); if (t >= off) c += y; }
        lst[t] = a - l0;
        lst[t + 64] = tot0 + c - l1;
    }
    __syncthreads();
    if (t < NPB) lcur[t] = lst[t];
    __syncthreads();
    if (fit) {
        #pragma unroll
        for (int i = 0; i < RPT; ++i) {
            if (pkreg[i] >= 0) {
                int slot = atomicAdd(&lcur[pkreg[i] & 127], 1);
                srcS[slot] = pkreg[i] >> 7;
            }
        }
    }
    __syncthreads();

    int w = t >> 6, L = t & 63, g = L >> 4, c = L & 15;
    int nbase = b * NPB;
    union { unsigned int u; __half2 h; } uc;
    for (int nl = w * 16; nl < w * 16 + 16; ++nl) {
        int node = nbase + nl;
        if (node >= n_nodes) break;
        int st = lst[nl];
        int deg = lh[nl];
        int en = st + deg;
        float ax = 0.f, ay = 0.f, az = 0.f, aw = 0.f;
        if (fit) {
            for (int eidx = st; eidx < en; eidx += 16) {
                int ea = eidx + g, eb = ea + 4, ec = ea + 8, ed = ea + 12;
                int sa = (ea < en) ? srcS[ea] : n_nodes;
                int sb = (eb < en) ? srcS[eb] : n_nodes;
                int sc = (ec < en) ? srcS[ec] : n_nodes;
                int sd = (ed < en) ? srcS[ed] : n_nodes;
                uint2 va = h2[(size_t)sa * 16 + c];
                uint2 vb = h2[(size_t)sb * 16 + c];
                uint2 vc = h2[(size_t)sc * 16 + c];
                uint2 vd = h2[(size_t)sd * 16 + c];
                float2 f;
                uc.u = va.x; f = __half22float2(uc.h); ax += f.x; ay += f.y;
                uc.u = va.y; f = __half22float2(uc.h); az += f.x; aw += f.y;
                uc.u = vb.x; f = __half22float2(uc.h); ax += f.x; ay += f.y;
                uc.u = vb.y; f = __half22float2(uc.h); az += f.x; aw += f.y;
                uc.u = vc.x; f = __half22float2(uc.h); ax += f.x; ay += f.y;
                uc.u = vc.y; f = __half22float2(uc.h); az += f.x; aw += f.y;
                uc.u = vd.x; f = __half22float2(uc.h); ax += f.x; ay += f.y;
                uc.u = vd.y; f = __half22float2(uc.h); az += f.x; aw += f.y;
            }
        } else {
            for (int i2 = g; i2 < cnt; i2 += 4) {
                int v = arrA[s + i2];
                if ((v & 127) == nl) {
                    int sa = v >> 7;
                    uint2 va = h2[(size_t)sa * 16 + c];
                    float2 f;
                    uc.u = va.x; f = __half22float2(uc.h); ax += f.x; ay += f.y;
                    uc.u = va.y; f = __half22float2(uc.h); az += f.x; aw += f.y;
                }
            }
        }
        ax += __shfl_xor(ax, 16); ay += __shfl_xor(ay, 16);
        az += __shfl_xor(az, 16); aw += __shfl_xor(aw, 16);
        ax += __shfl_xor(ax, 32); ay += __shfl_xor(ay, 32);
        az += __shfl_xor(az, 32); aw += __shfl_xor(aw, 32);
        if (g == 0) {
            float is = rsqrtf((float)(deg > 1 ? deg : 1));
            float4 r;
            r.x = ax * is; r.y = ay * is; r.z = az * is; r.w = aw * is;
            ((float4*)out)[(size_t)node * 16 + c] = r;
        }
    }
}

// ---------------- fallback: atomic scatter path (tiny ws) ----------------
__global__ void fb_zero(float* __restrict__ out, long long n_out,
                        int* __restrict__ deg, int n_deg) {
    long long i = (long long)blockIdx.x * blockDim.x + threadIdx.x;
    long long stride = (long long)gridDim.x * blockDim.x;
    for (long long j = i; j < n_out; j += stride) out[j] = 0.0f;
    for (long long j = i; j < n_deg; j += stride) deg[j] = 0;
}

__global__ void fb_degree(const int* __restrict__ src, const int* __restrict__ dst,
                          int n_edges, int* __restrict__ outdeg, int* __restrict__ indeg) {
    int i = blockIdx.x * blockDim.x + threadIdx.x;
    int stride = gridDim.x * blockDim.x;
    for (int e = i; e < n_edges; e += stride) {
        atomicAdd(&outdeg[src[e]], 1);
        atomicAdd(&indeg[dst[e]], 1);
    }
}

__global__ void fb_scatter(const float* __restrict__ emb,
                           const int* __restrict__ src, const int* __restrict__ dst,
                           const int* __restrict__ outdeg,
                           float* __restrict__ out, int n_edges) {
    const int epb = blockDim.x >> 6;
    const int d = threadIdx.x & 63;
    long long e0 = (long long)blockIdx.x * epb + (threadIdx.x >> 6);
    long long estride = (long long)gridDim.x * epb;
    for (long long e = e0; e < n_edges; e += estride) {
        int s = src[e];
        int tt = dst[e];
        int od = outdeg[s];
        float v = emb[(long long)s * D_FEAT + d] * rsqrtf((float)(od > 1 ? od : 1));
        atomicAdd(&out[(long long)tt * D_FEAT + d], v);
    }
}

__global__ void fb_scale(float* __restrict__ out, const int* __restrict__ indeg,
                         long long n_elems) {
    long long i = (long long)blockIdx.x * blockDim.x + threadIdx.x;
    long long stride = (long long)gridDim.x * blockDim.x;
    for (long long j = i; j < n_elems; j += stride) {
        int id = indeg[(int)(j >> 6)];
        out[j] *= rsqrtf((float)(id > 1 ? id : 1));
    }
}

extern "C" void kernel_launch(void* const* d_in, const int* in_sizes, int n_in,
                              void* d_out, int out_size, void* d_ws, size_t ws_size,
                              hipStream_t stream) {
    const float* emb = (const float*)d_in[0];
    const int* src = (const int*)d_in[1];
    const int* dst = (const int*)d_in[2];
    const int n_nodes = in_sizes[0] / D_FEAT;
    const int n_edges = in_sizes[1];
    float* out = (float*)d_out;
    const int block = 256;
    const int nb = (n_nodes + NPB - 1) / NPB;
    const int K = NBMAX;

    // layout (ints): dbcnt8 | sbcnt8 | dbstart | gcursor | sbstart | scursor |
    //                arrA | region{arrS bytes -> h2}
    int* dbcnt8 = (int*)d_ws;                        // 8K
    int* sbcnt8 = dbcnt8 + 8 * K;                    // 8K
    int* dbstart = sbcnt8 + 8 * K;                   // K+1
    int* gcursor = dbstart + K + 1;                  // K
    int* sbstart = gcursor + K;                      // K+1
    int* scursor = sbstart + K + 1;                  // K
    int* arrA = scursor + K;                         // E
    int* region = arrA + n_edges;                    // max(E/4, (N+1)*32) ints
    unsigned char* arrS = (unsigned char*)region;    // E bytes (dead after prep)
    uint2* h2 = (uint2*)region;                      // (N+1)*16 uint2

    size_t region_ints = (size_t)(n_nodes + 1) * 32;
    size_t arrS_ints = ((size_t)n_edges + 3) / 4;
    if (arrS_ints > region_ints) region_ints = arrS_ints;
    size_t need = (16 * (size_t)K + 2 * (size_t)(K + 1) + 2 * (size_t)K
                   + (size_t)n_edges + region_ints) * sizeof(int);

    if (ws_size >= need && nb <= K) {
        zero_ints<<<32, block, 0, stream>>>(dbcnt8, 16 * K);
        bcnt_kernel<<<384, block, 0, stream>>>(src, dst, n_edges, dbcnt8, sbcnt8);
        scan2_kernel<<<2, K, 0, stream>>>(dbcnt8, sbcnt8, dbstart, gcursor,
                                          sbstart, scursor, n_edges);
        int pblocks = (n_edges + CHUNK - 1) / CHUNK;
        dualpart_kernel<<<pblocks, 256, 0, stream>>>(src, dst, n_edges, gcursor,
                                                     scursor, arrA, arrS);
        prep_kernel<<<nb, 256, 0, stream>>>((const float4*)emb, arrS, sbstart,
                                            h2, n_nodes);
        sortagg_kernel<<<nb, 512, 0, stream>>>(h2, arrA, dbstart, out, n_nodes);
    } else {
        int* foutdeg = (int*)d_ws;
        int* findeg = foutdeg + n_nodes;
        long long n_out = (long long)n_nodes * D_FEAT;
        fb_zero<<<2048, block, 0, stream>>>(out, n_out, foutdeg, 2 * n_nodes);
        fb_degree<<<2048, block, 0, stream>>>(src, dst, n_edges, foutdeg, findeg);
        fb_scatter<<<2048, block, 0, stream>>>(emb, src, dst, foutdeg, out, n_edges);
        fb_scale<<<2048, block, 0, stream>>>(out, findeg, n_out);
    }
}

// Round 9
// 124.927 us; speedup vs baseline: 1.7345x; 1.7345x over previous
//
#include <hip/hip_runtime.h>
#include <hip/hip_fp16.h>

#define D_FEAT 64
#define NPB 128            // nodes per bucket (node >> 7)
#define NBMAX 1024         // padded bucket count (pow2)
#define CHUNK 4096         // edges per partition block (run length = CHUNK/NBMAX = 4)
#define EPT 16             // CHUNK / 256
#define CAPB 2816          // sortagg LDS edge capacity (mean 2046 + ~17 sigma)
#define RPT 6              // ceil(CAPB / 512)

// ---------------- zero ----------------
__global__ void zero_ints(int* __restrict__ p, int n) {
    int i = blockIdx.x * blockDim.x + threadIdx.x;
    int stride = gridDim.x * blockDim.x;
    for (int j = i; j < n; j += stride) p[j] = 0;
}

// ---------------- bucket counts for BOTH sides ----------------
__global__ __launch_bounds__(256) void bcnt_kernel(
        const int* __restrict__ src, const int* __restrict__ dst, int n_edges,
        int* __restrict__ dbcnt8, int* __restrict__ sbcnt8) {
    __shared__ int ld[NBMAX];
    __shared__ int ls[NBMAX];
    int t = threadIdx.x;
    for (int i = t; i < NBMAX; i += 256) { ld[i] = 0; ls[i] = 0; }
    __syncthreads();
    int i0 = blockIdx.x * blockDim.x + t;
    int stride = gridDim.x * blockDim.x;
    for (int e = i0; e < n_edges; e += stride) {
        atomicAdd(&ld[dst[e] >> 7], 1);
        atomicAdd(&ls[src[e] >> 7], 1);
    }
    __syncthreads();
    int* dmy = dbcnt8 + (blockIdx.x & 7) * NBMAX;
    int* smy = sbcnt8 + (blockIdx.x & 7) * NBMAX;
    for (int i = t; i < NBMAX; i += 256) {
        if (ld[i]) atomicAdd(&dmy[i], ld[i]);
        if (ls[i]) atomicAdd(&smy[i], ls[i]);
    }
}

// ---------------- dual exclusive scan: block 0 = dst side, block 1 = src side ----
__global__ void scan2_kernel(const int* __restrict__ dbcnt8, const int* __restrict__ sbcnt8,
                             int* __restrict__ dbstart, int* __restrict__ gcursor,
                             int* __restrict__ sbstart, int* __restrict__ scursor,
                             int n_edges) {
    __shared__ int wsum[16];
    int t = threadIdx.x, lane = t & 63, w = t >> 6;
    const int* c8 = (blockIdx.x == 0) ? dbcnt8 : sbcnt8;
    int* bs = (blockIdx.x == 0) ? dbstart : sbstart;
    int* cur = (blockIdx.x == 0) ? gcursor : scursor;
    int v = 0;
    #pragma unroll
    for (int c = 0; c < 8; ++c) v += c8[c * NBMAX + t];
    int inc = v;
    #pragma unroll
    for (int off = 1; off < 64; off <<= 1) {
        int y = __shfl_up(inc, off);
        if (lane >= off) inc += y;
    }
    if (lane == 63) wsum[w] = inc;
    __syncthreads();
    int add = 0;
    #pragma unroll
    for (int i = 0; i < 15; ++i) if (i < w) add += wsum[i];
    int ex = add + inc - v;
    bs[t] = ex;
    cur[t] = ex;
    if (t == NBMAX - 1) bs[NBMAX] = n_edges;
}

// ---------------- fused dual partition (round-7 proven version) ----------------
// Phase D: arrA[pk = (src<<7)|(dst&127)] bucketed by dst>>7
// Phase S: arrS[src&127 byte] bucketed by src>>7  (same LDS reused)
__global__ __launch_bounds__(256) void dualpart_kernel(
        const int* __restrict__ src, const int* __restrict__ dst, int n_edges,
        int* __restrict__ gcursor, int* __restrict__ scursor,
        int* __restrict__ arrA, unsigned char* __restrict__ arrS) {
    __shared__ int lhist[NBMAX];
    __shared__ int lstart[NBMAX];
    __shared__ int ldelta[NBMAX];
    __shared__ int lcur[NBMAX];
    __shared__ int part[256];
    __shared__ int pkLDS[CHUNK];
    __shared__ unsigned short bktLDS[CHUNK];

    int t = threadIdx.x;
    long long cbase = (long long)blockIdx.x * CHUNK;
    int cnt = (n_edges - cbase < CHUNK) ? (int)(n_edges - cbase) : CHUNK;

    for (int i = t; i < NBMAX; i += 256) lhist[i] = 0;
    __syncthreads();

    int ssrc[EPT], sdst[EPT];
    #pragma unroll
    for (int i = 0; i < EPT; ++i) {
        long long e = cbase + t + i * 256;
        if (e < n_edges) {
            ssrc[i] = src[e];
            sdst[i] = dst[e];
            atomicAdd(&lhist[sdst[i] >> 7], 1);
        } else {
            ssrc[i] = -1;
            sdst[i] = -1;
        }
    }
    __syncthreads();

    // ---- phase D scan ----
    int b0 = 4 * t;
    int h0 = lhist[b0], h1 = lhist[b0 + 1], h2v = lhist[b0 + 2], h3 = lhist[b0 + 3];
    int tot = h0 + h1 + h2v + h3;
    part[t] = tot;
    __syncthreads();
    for (int off = 1; off < 256; off <<= 1) {
        int x = (t >= off) ? part[t - off] : 0;
        __syncthreads();
        part[t] += x;
        __syncthreads();
    }
    int ex = part[t] - tot;
    lstart[b0] = ex;
    lstart[b0 + 1] = ex + h0;
    lstart[b0 + 2] = ex + h0 + h1;
    lstart[b0 + 3] = ex + h0 + h1 + h2v;
    __syncthreads();
    for (int b = t; b < NBMAX; b += 256) {
        lcur[b] = lstart[b];
        int c = lhist[b];
        if (c > 0) ldelta[b] = atomicAdd(&gcursor[b], c) - lstart[b];
    }
    __syncthreads();
    #pragma unroll
    for (int i = 0; i < EPT; ++i) {
        if (sdst[i] >= 0) {
            int b = sdst[i] >> 7;
            int slot = atomicAdd(&lcur[b], 1);
            pkLDS[slot] = (ssrc[i] << 7) | (sdst[i] & 127);
            bktLDS[slot] = (unsigned short)b;
        }
    }
    __syncthreads();
    for (int j = t; j < cnt; j += 256) {
        int b = bktLDS[j];
        arrA[j + ldelta[b]] = pkLDS[j];
    }
    __syncthreads();

    // ---- phase S (reuse all LDS) ----
    for (int i = t; i < NBMAX; i += 256) lhist[i] = 0;
    __syncthreads();
    #pragma unroll
    for (int i = 0; i < EPT; ++i) {
        if (ssrc[i] >= 0) atomicAdd(&lhist[ssrc[i] >> 7], 1);
    }
    __syncthreads();
    h0 = lhist[b0]; h1 = lhist[b0 + 1]; h2v = lhist[b0 + 2]; h3 = lhist[b0 + 3];
    tot = h0 + h1 + h2v + h3;
    part[t] = tot;
    __syncthreads();
    for (int off = 1; off < 256; off <<= 1) {
        int x = (t >= off) ? part[t - off] : 0;
        __syncthreads();
        part[t] += x;
        __syncthreads();
    }
    ex = part[t] - tot;
    lstart[b0] = ex;
    lstart[b0 + 1] = ex + h0;
    lstart[b0 + 2] = ex + h0 + h1;
    lstart[b0 + 3] = ex + h0 + h1 + h2v;
    __syncthreads();
    for (int b = t; b < NBMAX; b += 256) {
        lcur[b] = lstart[b];
        int c = lhist[b];
        if (c > 0) ldelta[b] = atomicAdd(&scursor[b], c) - lstart[b];
    }
    __syncthreads();
    unsigned char* stg = (unsigned char*)pkLDS;
    #pragma unroll
    for (int i = 0; i < EPT; ++i) {
        if (ssrc[i] >= 0) {
            int b = ssrc[i] >> 7;
            int slot = atomicAdd(&lcur[b], 1);
            stg[slot] = (unsigned char)(ssrc[i] & 127);
            bktLDS[slot] = (unsigned short)b;
        }
    }
    __syncthreads();
    for (int j = t; j < cnt; j += 256) {
        int b = bktLDS[j];
        arrS[j + ldelta[b]] = stg[j];
    }
}

// ---------------- fused out-degree + h prepass: one block per src bucket ----------
__global__ __launch_bounds__(256) void prep_kernel(
        const float4* __restrict__ emb4, const unsigned char* __restrict__ arrS,
        const int* __restrict__ sbstart, uint2* __restrict__ h2, int n_nodes) {
    __shared__ int lh[NPB];
    __shared__ float lsc[NPB];
    int b = blockIdx.x, t = threadIdx.x;
    int s = sbstart[b], e = sbstart[b + 1];
    if (t < NPB) lh[t] = 0;
    __syncthreads();
    for (int i = s + t; i < e; i += 256) atomicAdd(&lh[arrS[i]], 1);
    __syncthreads();
    if (t < NPB) {
        int od = lh[t];
        lsc[t] = rsqrtf((float)(od > 1 ? od : 1));
    }
    __syncthreads();
    int nbase = b * NPB;
    int r = t >> 4, c = t & 15;
    for (int r0 = 0; r0 < NPB; r0 += 16) {
        int row = r0 + r;
        int node = nbase + row;
        if (node < n_nodes) {
            float sc = lsc[row];
            float4 v = emb4[(size_t)node * 16 + c];
            __half2 a = __floats2half2_rn(v.x * sc, v.y * sc);
            __half2 bb = __floats2half2_rn(v.z * sc, v.w * sc);
            union { __half2 h; unsigned int u; } ua, ub;
            ua.h = a; ub.h = bb;
            uint2 rr; rr.x = ua.u; rr.y = ub.u;
            h2[(size_t)node * 16 + c] = rr;
        }
    }
    if (b == 0 && t < 16) {
        uint2 z; z.x = 0; z.y = 0;
        h2[(size_t)n_nodes * 16 + t] = z;
    }
}

// ---------------- fused sort + aggregate: one block per dst bucket ----------------
__global__ __launch_bounds__(512) void sortagg_kernel(
        const uint2* __restrict__ h2, const int* __restrict__ arrA,
        const int* __restrict__ dbstart, float* __restrict__ out, int n_nodes) {
    __shared__ int lh[NPB];
    __shared__ int lst[NPB];
    __shared__ int lcur[NPB];
    __shared__ int srcS[CAPB];
    int b = blockIdx.x, t = threadIdx.x;
    int s = dbstart[b], e = dbstart[b + 1];
    int cnt = e - s;
    bool fit = (cnt <= CAPB);

    if (t < NPB) lh[t] = 0;
    __syncthreads();
    int pkreg[RPT];
    if (fit) {
        #pragma unroll
        for (int i = 0; i < RPT; ++i) {
            int idx = t + i * 512;
            pkreg[i] = (idx < cnt) ? arrA[s + idx] : -1;
            if (pkreg[i] >= 0) atomicAdd(&lh[pkreg[i] & 127], 1);
        }
    } else {
        for (int i = t; i < cnt; i += 512) atomicAdd(&lh[arrA[s + i] & 127], 1);
    }
    __syncthreads();
    if (t < 64) {
        int l0 = lh[t], l1 = lh[t + 64];
        int a = l0;
        for (int off = 1; off < 64; off <<= 1) { int y = __shfl_up(a, off); if (t >= off) a += y; }
        int tot0 = __shfl(a, 63);
        int c = l1;
        for (int off = 1; off < 64; off <<= 1) { int y = __shfl_up(c, off); if (t >= off) c += y; }
        lst[t] = a - l0;
        lst[t + 64] = tot0 + c - l1;
    }
    __syncthreads();
    if (t < NPB) lcur[t] = lst[t];
    __syncthreads();
    if (fit) {
        #pragma unroll
        for (int i = 0; i < RPT; ++i) {
            if (pkreg[i] >= 0) {
                int slot = atomicAdd(&lcur[pkreg[i] & 127], 1);
                srcS[slot] = pkreg[i] >> 7;
            }
        }
    }
    __syncthreads();

    int w = t >> 6, L = t & 63, g = L >> 4, c = L & 15;
    int nbase = b * NPB;
    union { unsigned int u; __half2 h; } uc;
    for (int nl = w * 16; nl < w * 16 + 16; ++nl) {
        int node = nbase + nl;
        if (node >= n_nodes) break;
        int st = lst[nl];
        int deg = lh[nl];
        int en = st + deg;
        float ax = 0.f, ay = 0.f, az = 0.f, aw = 0.f;
        if (fit) {
            for (int eidx = st; eidx < en; eidx += 16) {
                int ea = eidx + g, eb = ea + 4, ec = ea + 8, ed = ea + 12;
                int sa = (ea < en) ? srcS[ea] : n_nodes;
                int sb = (eb < en) ? srcS[eb] : n_nodes;
                int sc = (ec < en) ? srcS[ec] : n_nodes;
                int sd = (ed < en) ? srcS[ed] : n_nodes;
                uint2 va = h2[(size_t)sa * 16 + c];
                uint2 vb = h2[(size_t)sb * 16 + c];
                uint2 vc = h2[(size_t)sc * 16 + c];
                uint2 vd = h2[(size_t)sd * 16 + c];
                float2 f;
                uc.u = va.x; f = __half22float2(uc.h); ax += f.x; ay += f.y;
                uc.u = va.y; f = __half22float2(uc.h); az += f.x; aw += f.y;
                uc.u = vb.x; f = __half22float2(uc.h); ax += f.x; ay += f.y;
                uc.u = vb.y; f = __half22float2(uc.h); az += f.x; aw += f.y;
                uc.u = vc.x; f = __half22float2(uc.h); ax += f.x; ay += f.y;
                uc.u = vc.y; f = __half22float2(uc.h); az += f.x; aw += f.y;
                uc.u = vd.x; f = __half22float2(uc.h); ax += f.x; ay += f.y;
                uc.u = vd.y; f = __half22float2(uc.h); az += f.x; aw += f.y;
            }
        } else {
            for (int i2 = g; i2 < cnt; i2 += 4) {
                int v = arrA[s + i2];
                if ((v & 127) == nl) {
                    int sa = v >> 7;
                    uint2 va = h2[(size_t)sa * 16 + c];
                    float2 f;
                    uc.u = va.x; f = __half22float2(uc.h); ax += f.x; ay += f.y;
                    uc.u = va.y; f = __half22float2(uc.h); az += f.x; aw += f.y;
                }
            }
        }
        ax += __shfl_xor(ax, 16); ay += __shfl_xor(ay, 16);
        az += __shfl_xor(az, 16); aw += __shfl_xor(aw, 16);
        ax += __shfl_xor(ax, 32); ay += __shfl_xor(ay, 32);
        az += __shfl_xor(az, 32); aw += __shfl_xor(aw, 32);
        if (g == 0) {
            float is = rsqrtf((float)(deg > 1 ? deg : 1));
            float4 r;
            r.x = ax * is; r.y = ay * is; r.z = az * is; r.w = aw * is;
            ((float4*)out)[(size_t)node * 16 + c] = r;
        }
    }
}

// ---------------- fallback: atomic scatter path (tiny ws) ----------------
__global__ void fb_zero(float* __restrict__ out, long long n_out,
                        int* __restrict__ deg, int n_deg) {
    long long i = (long long)blockIdx.x * blockDim.x + threadIdx.x;
    long long stride = (long long)gridDim.x * blockDim.x;
    for (long long j = i; j < n_out; j += stride) out[j] = 0.0f;
    for (long long j = i; j < n_deg; j += stride) deg[j] = 0;
}

__global__ void fb_degree(const int* __restrict__ src, const int* __restrict__ dst,
                          int n_edges, int* __restrict__ outdeg, int* __restrict__ indeg) {
    int i = blockIdx.x * blockDim.x + threadIdx.x;
    int stride = gridDim.x * blockDim.x;
    for (int e = i; e < n_edges; e += stride) {
        atomicAdd(&outdeg[src[e]], 1);
        atomicAdd(&indeg[dst[e]], 1);
    }
}

__global__ void fb_scatter(const float* __restrict__ emb,
                           const int* __restrict__ src, const int* __restrict__ dst,
                           const int* __restrict__ outdeg,
                           float* __restrict__ out, int n_edges) {
    const int epb = blockDim.x >> 6;
    const int d = threadIdx.x & 63;
    long long e0 = (long long)blockIdx.x * epb + (threadIdx.x >> 6);
    long long estride = (long long)gridDim.x * epb;
    for (long long e = e0; e < n_edges; e += estride) {
        int s = src[e];
        int tt = dst[e];
        int od = outdeg[s];
        float v = emb[(long long)s * D_FEAT + d] * rsqrtf((float)(od > 1 ? od : 1));
        atomicAdd(&out[(long long)tt * D_FEAT + d], v);
    }
}

__global__ void fb_scale(float* __restrict__ out, const int* __restrict__ indeg,
                         long long n_elems) {
    long long i = (long long)blockIdx.x * blockDim.x + threadIdx.x;
    long long stride = (long long)gridDim.x * blockDim.x;
    for (long long j = i; j < n_elems; j += stride) {
        int id = indeg[(int)(j >> 6)];
        out[j] *= rsqrtf((float)(id > 1 ? id : 1));
    }
}

extern "C" void kernel_launch(void* const* d_in, const int* in_sizes, int n_in,
                              void* d_out, int out_size, void* d_ws, size_t ws_size,
                              hipStream_t stream) {
    const float* emb = (const float*)d_in[0];
    const int* src = (const int*)d_in[1];
    const int* dst = (const int*)d_in[2];
    const int n_nodes = in_sizes[0] / D_FEAT;
    const int n_edges = in_sizes[1];
    float* out = (float*)d_out;
    const int block = 256;
    const int nb = (n_nodes + NPB - 1) / NPB;
    const int K = NBMAX;

    // layout (ints): dbcnt8 | sbcnt8 | dbstart | gcursor | sbstart | scursor |
    //                arrA | region{arrS bytes -> h2}
    int* dbcnt8 = (int*)d_ws;                        // 8K
    int* sbcnt8 = dbcnt8 + 8 * K;                    // 8K
    int* dbstart = sbcnt8 + 8 * K;                   // K+1
    int* gcursor = dbstart + K + 1;                  // K
    int* sbstart = gcursor + K;                      // K+1
    int* scursor = sbstart + K + 1;                  // K
    int* arrA = scursor + K;                         // E
    int* region = arrA + n_edges;                    // max(E/4, (N+1)*32) ints
    unsigned char* arrS = (unsigned char*)region;    // E bytes (dead after prep)
    uint2* h2 = (uint2*)region;                      // (N+1)*16 uint2

    size_t region_ints = (size_t)(n_nodes + 1) * 32;
    size_t arrS_ints = ((size_t)n_edges + 3) / 4;
    if (arrS_ints > region_ints) region_ints = arrS_ints;
    size_t need = (16 * (size_t)K + 2 * (size_t)(K + 1) + 2 * (size_t)K
                   + (size_t)n_edges + region_ints) * sizeof(int);

    if (ws_size >= need && nb <= K) {
        zero_ints<<<32, block, 0, stream>>>(dbcnt8, 16 * K);
        bcnt_kernel<<<384, block, 0, stream>>>(src, dst, n_edges, dbcnt8, sbcnt8);
        scan2_kernel<<<2, K, 0, stream>>>(dbcnt8, sbcnt8, dbstart, gcursor,
                                          sbstart, scursor, n_edges);
        int pblocks = (n_edges + CHUNK - 1) / CHUNK;
        dualpart_kernel<<<pblocks, 256, 0, stream>>>(src, dst, n_edges, gcursor,
                                                     scursor, arrA, arrS);
        prep_kernel<<<nb, 256, 0, stream>>>((const float4*)emb, arrS, sbstart,
                                            h2, n_nodes);
        sortagg_kernel<<<nb, 512, 0, stream>>>(h2, arrA, dbstart, out, n_nodes);
    } else {
        int* foutdeg = (int*)d_ws;
        int* findeg = foutdeg + n_nodes;
        long long n_out = (long long)n_nodes * D_FEAT;
        fb_zero<<<2048, block, 0, stream>>>(out, n_out, foutdeg, 2 * n_nodes);
        fb_degree<<<2048, block, 0, stream>>>(src, dst, n_edges, foutdeg, findeg);
        fb_scatter<<<2048, block, 0, stream>>>(emb, src, dst, foutdeg, out, n_edges);
        fb_scale<<<2048, block, 0, stream>>>(out, findeg, n_out);
    }
}